// Round 12
// baseline (850.666 us; speedup 1.0000x reference)
//
#include <hip/hip_runtime.h>

// Fused Conv1d(k=3,pad=1) + BN(inference) + 4-step LIF + residual.
// x: (L=2048, TB=128, D=128) f32. conv_w: (D,D,3). out: (L,TB,D) f32.
//
// R14 = R12 structure with the launch-bound bug fixed: R7 inner loop
// UNCHANGED (ob=4, transposed conflict-free ws, LT=64, JT=8) + xs halved
// via channel-chunking (chunk0 @ it=0, chunk1 @ it=8, inside existing
// barrier phases). LDS 29.2 KB; __launch_bounds__(256,3) -> 84 VGPRs
// (proven no-spill env; (.,4) clamps to 64 -> R11/R12 scratch disaster).
// Grid 1024 = exactly 4 resident blocks/CU (16 waves, 4/SIMD) vs R7's
// ~2.2 blocks — the single-variable occupancy test of the latency-
// exposure theory. Residual re-read from global (L2-hot).
// Per-(o,l) FMA order bit-identical to R3/R7 (absmax must stay 0.0).

constexpr int L   = 2048;
constexpr int NTB = 128;
constexpr int D   = 128;
constexpr int T   = 4;
constexpr int LT  = 64;        // l-tile per block
constexpr int NP  = LT + 2;    // 66 staged positions (halo)
constexpr int JT  = 8;         // l-positions per thread (2 groups x 8 per wave)

__global__ __launch_bounds__(256, 3)
void snn_conv_lif(const float* __restrict__ x, const float* __restrict__ w,
                  const float* __restrict__ gamma, const float* __restrict__ beta,
                  const float* __restrict__ mean, const float* __restrict__ var,
                  float* __restrict__ out) {
    __shared__ float xs[NP * 64];       // 16896 B: one 64-channel chunk
    __shared__ float ws[768 * 4];       // 12288 B: [(oo*6+f)*32+qq] float4
                                        // total 29184 B -> 5 blocks LDS-capable

    const int tid = threadIdx.x;
    const int b   = blockIdx.x & 31;
    const int lt  = blockIdx.x >> 5;
    const int l0  = lt * LT;
    const int q4  = tid & 31;                                 // o-quad
    const int p0  = (tid >> 6) * 16 + ((tid >> 5) & 1) * JT;  // l-group base
    const float4* x4 = (const float4*)x;

    float sc[4], bi[4];
    {
        const float4 g4 = ((const float4*)gamma)[q4];
        const float4 b4 = ((const float4*)beta)[q4];
        const float4 m4 = ((const float4*)mean)[q4];
        const float4 v4 = ((const float4*)var)[q4];
        const float gg[4] = {g4.x, g4.y, g4.z, g4.w};
        const float bb[4] = {b4.x, b4.y, b4.z, b4.w};
        const float mm[4] = {m4.x, m4.y, m4.z, m4.w};
        const float vv[4] = {v4.x, v4.y, v4.z, v4.w};
        #pragma unroll
        for (int oo = 0; oo < 4; ++oo) {
            sc[oo] = gg[oo] / sqrtf(vv[oo] + 1e-5f);
            bi[oo] = bb[oo] - mm[oo] * sc[oo];
        }
    }

    float v[4][JT];
    #pragma unroll
    for (int oo = 0; oo < 4; ++oo)
        #pragma unroll
        for (int j = 0; j < JT; ++j) v[oo][j] = 0.f;

    #pragma unroll 1
    for (int t = 0; t < T; ++t) {
        const int n = t * 32 + b;

        float a[4][JT];
        #pragma unroll
        for (int oo = 0; oo < 4; ++oo)
            #pragma unroll
            for (int j = 0; j < JT; ++j) a[oo][j] = 0.f;

        #pragma unroll 1
        for (int it = 0; it < 16; ++it) {
            __syncthreads();  // previous ws/xs readers done
            // ---- stage weight tile it (identical to R7) ----
            #pragma unroll
            for (int r = 0; r < 3; ++r) {
                const int idx = tid + r * 256;
                const int qq  = idx & 31;
                const int cc  = idx >> 5;          // 0..23
                const int f   = cc >> 2;           // 0..5
                const int oo  = cc & 3;            // 0..3
                const float4 wv = *((const float4*)(w + (4 * qq + oo) * (D * 3) + it * 24 + f * 4));
                *((float4*)(ws + ((oo * 6 + f) * 32 + qq) * 4)) = wv;
            }
            // ---- stage x chunk at it==0 (ch 0..63) and it==8 (ch 64..127) ----
            if ((it & 7) == 0) {
                const int cb = (it >> 3) * 16;     // chunk base, float4 units
                for (int idx = tid; idx < NP * 16; idx += 256) {
                    const int p = idx >> 4, c = idx & 15;
                    const int ll = l0 - 1 + p;
                    float4 val = make_float4(0.f, 0.f, 0.f, 0.f);
                    if (ll >= 0 && ll < L)
                        val = x4[(ll * NTB + n) * 32 + cb + c];
                    ((float4*)xs)[p * 16 + c] = val;
                }
            }
            __syncthreads();

            #pragma unroll
            for (int i4 = 0; i4 < 2; ++i4) {
                float4 W0[4], W1[4], W2[4];
                #pragma unroll
                for (int oo = 0; oo < 4; ++oo) {
                    const float* wpt = ws + ((oo * 6 + i4 * 3) * 32 + q4) * 4;
                    W0[oo] = *((const float4*)(wpt));
                    W1[oo] = *((const float4*)(wpt + 128));
                    W2[oo] = *((const float4*)(wpt + 256));
                }

                const int iic = (it & 7) * 2 + i4;             // chunk-local group
                const float4* xcol = (const float4*)xs + iic;  // stride 16/pos
                float4 xa = xcol[(p0 + 0) * 16];
                float4 xb = xcol[(p0 + 1) * 16];
                #pragma unroll
                for (int j = 0; j < JT; ++j) {
                    const float4 xc = xcol[(p0 + j + 2) * 16];
                    #pragma unroll
                    for (int oo = 0; oo < 4; ++oo) {
                        float s = a[oo][j];
                        const float4 w0 = W0[oo], w1 = W1[oo], w2 = W2[oo];
                        s = fmaf(xa.x, w0.x, s);   // k=0, i+0
                        s = fmaf(xa.y, w0.w, s);   // k=0, i+1
                        s = fmaf(xa.z, w1.z, s);   // k=0, i+2
                        s = fmaf(xa.w, w2.y, s);   // k=0, i+3
                        s = fmaf(xb.x, w0.y, s);   // k=1, i+0
                        s = fmaf(xb.y, w1.x, s);   // k=1, i+1
                        s = fmaf(xb.z, w1.w, s);   // k=1, i+2
                        s = fmaf(xb.w, w2.z, s);   // k=1, i+3
                        s = fmaf(xc.x, w0.z, s);   // k=2, i+0
                        s = fmaf(xc.y, w1.y, s);   // k=2, i+1
                        s = fmaf(xc.z, w2.x, s);   // k=2, i+2
                        s = fmaf(xc.w, w2.w, s);   // k=2, i+3
                        a[oo][j] = s;
                    }
                    xa = xb; xb = xc;
                }
            }
        }

        // ---- BN + LIF + residual (from global, L2-hot) + float4 store ----
        #pragma unroll
        for (int j = 0; j < JT; ++j) {
            const int l = l0 + p0 + j;
            const float4 res = x4[(l * NTB + n) * 32 + q4];
            const float rr[4] = {res.x, res.y, res.z, res.w};
            float ov[4];
            #pragma unroll
            for (int oo = 0; oo < 4; ++oo) {
                const float y = fmaf(a[oo][j], sc[oo], bi[oo]);
                const float h = 0.5f * (v[oo][j] + y);     // v + (y - v)/tau, tau=2
                const bool fire = (h >= 1.0f);
                v[oo][j] = fire ? 0.0f : h;                // hard reset
                ov[oo] = rr[oo] + (fire ? 1.0f : 0.0f);
            }
            ((float4*)out)[(l * NTB + n) * 32 + q4] =
                make_float4(ov[0], ov[1], ov[2], ov[3]);
        }
    }
}

extern "C" void kernel_launch(void* const* d_in, const int* in_sizes, int n_in,
                              void* d_out, int out_size, void* d_ws, size_t ws_size,
                              hipStream_t stream) {
    const float* x     = (const float*)d_in[0];
    const float* w     = (const float*)d_in[1];
    const float* gamma = (const float*)d_in[2];
    const float* beta  = (const float*)d_in[3];
    const float* mean  = (const float*)d_in[4];
    const float* var   = (const float*)d_in[5];
    float* out = (float*)d_out;

    dim3 grid((L / LT) * 32);   // 32 l-tiles x 32 b values = 1024 blocks (4/CU)
    dim3 block(256);
    snn_conv_lif<<<grid, block, 0, stream>>>(x, w, gamma, beta, mean, var, out);
}

// Round 13
// 570.439 us; speedup vs baseline: 1.4912x; 1.4912x over previous
//
#include <hip/hip_runtime.h>

// Fused Conv1d(k=3,pad=1) + BN(inference) + 4-step LIF + residual.
// x: (L=2048, TB=128, D=128) f32. conv_w: (D,D,3). out: (L,TB,D) f32.
//
// R15 = R14's occupancy experiment with the codegen poison removed: the
// channel-chunked x staging is STRAIGHT-LINE (two 8-step it-halves, each
// preceded unconditionally by its chunk's staging) instead of an if()
// inside the it-loop (which triggered ~740MB of scratch despite VGPR=84
// and capped residency — R14). Inner loop textually identical to R7.
// LDS 29.2 KB -> 4 resident blocks/CU (grid 1024 = exactly 4/CU,
// 4 waves/SIMD vs R7's ~2.2 blocks) at R7's proven 84-VGPR allocation.
// Residual re-read from global (L2-hot). Per-(o,l) FMA order bit-identical
// to R3/R7 (absmax must stay 0.0).

constexpr int L   = 2048;
constexpr int NTB = 128;
constexpr int D   = 128;
constexpr int T   = 4;
constexpr int LT  = 64;        // l-tile per block
constexpr int NP  = LT + 2;    // 66 staged positions (halo)
constexpr int JT  = 8;         // l-positions per thread (2 groups x 8 per wave)

__global__ __launch_bounds__(256, 3)
void snn_conv_lif(const float* __restrict__ x, const float* __restrict__ w,
                  const float* __restrict__ gamma, const float* __restrict__ beta,
                  const float* __restrict__ mean, const float* __restrict__ var,
                  float* __restrict__ out) {
    __shared__ float xs[NP * 64];       // 16896 B: one 64-channel chunk
    __shared__ float ws[768 * 4];       // 12288 B: [(oo*6+f)*32+qq] float4
                                        // total 29184 B

    const int tid = threadIdx.x;
    const int b   = blockIdx.x & 31;
    const int lt  = blockIdx.x >> 5;
    const int l0  = lt * LT;
    const int q4  = tid & 31;                                 // o-quad
    const int p0  = (tid >> 6) * 16 + ((tid >> 5) & 1) * JT;  // l-group base
    const float4* x4 = (const float4*)x;

    float sc[4], bi[4];
    {
        const float4 g4 = ((const float4*)gamma)[q4];
        const float4 b4 = ((const float4*)beta)[q4];
        const float4 m4 = ((const float4*)mean)[q4];
        const float4 v4 = ((const float4*)var)[q4];
        const float gg[4] = {g4.x, g4.y, g4.z, g4.w};
        const float bb[4] = {b4.x, b4.y, b4.z, b4.w};
        const float mm[4] = {m4.x, m4.y, m4.z, m4.w};
        const float vv[4] = {v4.x, v4.y, v4.z, v4.w};
        #pragma unroll
        for (int oo = 0; oo < 4; ++oo) {
            sc[oo] = gg[oo] / sqrtf(vv[oo] + 1e-5f);
            bi[oo] = bb[oo] - mm[oo] * sc[oo];
        }
    }

    float v[4][JT];
    #pragma unroll
    for (int oo = 0; oo < 4; ++oo)
        #pragma unroll
        for (int j = 0; j < JT; ++j) v[oo][j] = 0.f;

    #pragma unroll 1
    for (int t = 0; t < T; ++t) {
        const int n = t * 32 + b;

        float a[4][JT];
        #pragma unroll
        for (int oo = 0; oo < 4; ++oo)
            #pragma unroll
            for (int j = 0; j < JT; ++j) a[oo][j] = 0.f;

        #pragma unroll 1
        for (int half = 0; half < 2; ++half) {
            // ---- stage x chunk (straight-line, unconditional) ----
            __syncthreads();   // previous chunk's / prev-t's xs readers done
            const int cb = half * 16;   // chunk channel base, float4 units
            for (int idx = tid; idx < NP * 16; idx += 256) {
                const int p = idx >> 4, c = idx & 15;
                const int ll = l0 - 1 + p;
                float4 val = make_float4(0.f, 0.f, 0.f, 0.f);
                if (ll >= 0 && ll < L)
                    val = x4[(ll * NTB + n) * 32 + cb + c];
                ((float4*)xs)[p * 16 + c] = val;
            }

            #pragma unroll 1
            for (int itl = 0; itl < 8; ++itl) {
                const int it = half * 8 + itl;    // global weight tile
                __syncthreads();  // ws readers done (covers xs stage at itl==0)
                // ---- stage weight tile it (identical to R7) ----
                #pragma unroll
                for (int r = 0; r < 3; ++r) {
                    const int idx = tid + r * 256;
                    const int qq  = idx & 31;
                    const int cc  = idx >> 5;          // 0..23
                    const int f   = cc >> 2;           // 0..5
                    const int oo  = cc & 3;            // 0..3
                    const float4 wv = *((const float4*)(w + (4 * qq + oo) * (D * 3) + it * 24 + f * 4));
                    *((float4*)(ws + ((oo * 6 + f) * 32 + qq) * 4)) = wv;
                }
                __syncthreads();

                #pragma unroll
                for (int i4 = 0; i4 < 2; ++i4) {
                    float4 W0[4], W1[4], W2[4];
                    #pragma unroll
                    for (int oo = 0; oo < 4; ++oo) {
                        const float* wpt = ws + ((oo * 6 + i4 * 3) * 32 + q4) * 4;
                        W0[oo] = *((const float4*)(wpt));
                        W1[oo] = *((const float4*)(wpt + 128));
                        W2[oo] = *((const float4*)(wpt + 256));
                    }

                    const int iic = itl * 2 + i4;                  // chunk-local group
                    const float4* xcol = (const float4*)xs + iic;  // stride 16/pos
                    float4 xa = xcol[(p0 + 0) * 16];
                    float4 xb = xcol[(p0 + 1) * 16];
                    #pragma unroll
                    for (int j = 0; j < JT; ++j) {
                        const float4 xc = xcol[(p0 + j + 2) * 16];
                        #pragma unroll
                        for (int oo = 0; oo < 4; ++oo) {
                            float s = a[oo][j];
                            const float4 w0 = W0[oo], w1 = W1[oo], w2 = W2[oo];
                            s = fmaf(xa.x, w0.x, s);   // k=0, i+0
                            s = fmaf(xa.y, w0.w, s);   // k=0, i+1
                            s = fmaf(xa.z, w1.z, s);   // k=0, i+2
                            s = fmaf(xa.w, w2.y, s);   // k=0, i+3
                            s = fmaf(xb.x, w0.y, s);   // k=1, i+0
                            s = fmaf(xb.y, w1.x, s);   // k=1, i+1
                            s = fmaf(xb.z, w1.w, s);   // k=1, i+2
                            s = fmaf(xb.w, w2.z, s);   // k=1, i+3
                            s = fmaf(xc.x, w0.z, s);   // k=2, i+0
                            s = fmaf(xc.y, w1.y, s);   // k=2, i+1
                            s = fmaf(xc.z, w2.x, s);   // k=2, i+2
                            s = fmaf(xc.w, w2.w, s);   // k=2, i+3
                            a[oo][j] = s;
                        }
                        xa = xb; xb = xc;
                    }
                }
            }
        }

        // ---- BN + LIF + residual (from global, L2-hot) + float4 store ----
        #pragma unroll
        for (int j = 0; j < JT; ++j) {
            const int l = l0 + p0 + j;
            const float4 res = x4[(l * NTB + n) * 32 + q4];
            const float rr[4] = {res.x, res.y, res.z, res.w};
            float ov[4];
            #pragma unroll
            for (int oo = 0; oo < 4; ++oo) {
                const float y = fmaf(a[oo][j], sc[oo], bi[oo]);
                const float h = 0.5f * (v[oo][j] + y);     // v + (y - v)/tau, tau=2
                const bool fire = (h >= 1.0f);
                v[oo][j] = fire ? 0.0f : h;                // hard reset
                ov[oo] = rr[oo] + (fire ? 1.0f : 0.0f);
            }
            ((float4*)out)[(l * NTB + n) * 32 + q4] =
                make_float4(ov[0], ov[1], ov[2], ov[3]);
        }
    }
}

extern "C" void kernel_launch(void* const* d_in, const int* in_sizes, int n_in,
                              void* d_out, int out_size, void* d_ws, size_t ws_size,
                              hipStream_t stream) {
    const float* x     = (const float*)d_in[0];
    const float* w     = (const float*)d_in[1];
    const float* gamma = (const float*)d_in[2];
    const float* beta  = (const float*)d_in[3];
    const float* mean  = (const float*)d_in[4];
    const float* var   = (const float*)d_in[5];
    float* out = (float*)d_out;

    dim3 grid((L / LT) * 32);   // 32 l-tiles x 32 b values = 1024 blocks (4/CU)
    dim3 block(256);
    snn_conv_lif<<<grid, block, 0, stream>>>(x, w, gamma, beta, mean, var, out);
}

// Round 14
// 543.312 us; speedup vs baseline: 1.5657x; 1.0499x over previous
//
#include <hip/hip_runtime.h>

// Fused Conv1d(k=3,pad=1) + BN(inference) + 4-step LIF + residual.
// x: (L=2048, TB=128, D=128) f32. conv_w: (D,D,3). out: (L,TB,D) f32.
//
// R16 = R15 (chunked xs, straight-line staging, R7 inner loop) with the
// bulk-synchronous 2-barrier tile loop replaced by a DOUBLE-BUFFERED ws
// pipeline: per tile, issue next tile's 3 global loads (unconditional,
// wrap-indexed (it+1)&15), compute tile it from buf[it&1], ds_write the
// prefetch into buf[(it+1)&1] (disjoint region, no pre-barrier), ONE
// __syncthreads. Barriers 132 -> 73/block; staging latency hides under
// ~768 FMA cycles; wrap makes t+1's tile-0 staging free. All loads
// unconditional (R6/R9/R14 scratch-demotion lesson). Per-(o,l) FMA order
// bit-identical to R3/R7 (absmax must stay 0.0).

constexpr int L   = 2048;
constexpr int NTB = 128;
constexpr int D   = 128;
constexpr int T   = 4;
constexpr int LT  = 64;        // l-tile per block
constexpr int NP  = LT + 2;    // 66 staged positions (halo)
constexpr int JT  = 8;         // l-positions per thread (2 groups x 8 per wave)

__global__ __launch_bounds__(256, 3)
void snn_conv_lif(const float* __restrict__ x, const float* __restrict__ w,
                  const float* __restrict__ gamma, const float* __restrict__ beta,
                  const float* __restrict__ mean, const float* __restrict__ var,
                  float* __restrict__ out) {
    __shared__ float xs[NP * 64];       // 16896 B: one 64-channel chunk
    __shared__ float ws[2][768 * 4];    // 24576 B: double-buffered weight tile
                                        // total 41472 B

    const int tid = threadIdx.x;
    const int b   = blockIdx.x & 31;
    const int lt  = blockIdx.x >> 5;
    const int l0  = lt * LT;
    const int q4  = tid & 31;                                 // o-quad
    const int p0  = (tid >> 6) * 16 + ((tid >> 5) & 1) * JT;  // l-group base
    const float4* x4 = (const float4*)x;

    // per-thread staging map (same transposed layout as R7)
    int wgoff[3], wloff[3];
    #pragma unroll
    for (int r = 0; r < 3; ++r) {
        const int idx = tid + r * 256;
        const int qq  = idx & 31;
        const int cc  = idx >> 5;          // 0..23
        const int f   = cc >> 2;           // 0..5
        const int oo  = cc & 3;            // 0..3
        wgoff[r] = (4 * qq + oo) * (D * 3) + f * 4;          // + it*24
        wloff[r] = ((oo * 6 + f) * 32 + qq) * 4;
    }

    float sc[4], bi[4];
    {
        const float4 g4 = ((const float4*)gamma)[q4];
        const float4 b4 = ((const float4*)beta)[q4];
        const float4 m4 = ((const float4*)mean)[q4];
        const float4 v4 = ((const float4*)var)[q4];
        const float gg[4] = {g4.x, g4.y, g4.z, g4.w};
        const float bb[4] = {b4.x, b4.y, b4.z, b4.w};
        const float mm[4] = {m4.x, m4.y, m4.z, m4.w};
        const float vv[4] = {v4.x, v4.y, v4.z, v4.w};
        #pragma unroll
        for (int oo = 0; oo < 4; ++oo) {
            sc[oo] = gg[oo] / sqrtf(vv[oo] + 1e-5f);
            bi[oo] = bb[oo] - mm[oo] * sc[oo];
        }
    }

    float v[4][JT];
    #pragma unroll
    for (int oo = 0; oo < 4; ++oo)
        #pragma unroll
        for (int j = 0; j < JT; ++j) v[oo][j] = 0.f;

    // ---- prologue: stage weight tile 0 into buf 0 (barrier comes below) ----
    #pragma unroll
    for (int r = 0; r < 3; ++r)
        *((float4*)(&ws[0][wloff[r]])) = *((const float4*)(w + wgoff[r]));

    #pragma unroll 1
    for (int t = 0; t < T; ++t) {
        const int n = t * 32 + b;

        float a[4][JT];
        #pragma unroll
        for (int oo = 0; oo < 4; ++oo)
            #pragma unroll
            for (int j = 0; j < JT; ++j) a[oo][j] = 0.f;

        #pragma unroll 1
        for (int half = 0; half < 2; ++half) {
            // ---- stage x chunk (prior itl-loop trailing barrier gates reuse) ----
            const int cb = half * 16;   // chunk channel base, float4 units
            for (int idx = tid; idx < NP * 16; idx += 256) {
                const int p = idx >> 4, c = idx & 15;
                const int ll = l0 - 1 + p;
                float4 val = make_float4(0.f, 0.f, 0.f, 0.f);
                if (ll >= 0 && ll < L)
                    val = x4[(ll * NTB + n) * 32 + cb + c];
                ((float4*)xs)[p * 16 + c] = val;
            }
            __syncthreads();   // xs + current ws buffer ready

            #pragma unroll 1
            for (int itl = 0; itl < 8; ++itl) {
                const int it  = half * 8 + itl;    // global weight tile
                const int itn = (it + 1) & 15;     // wrap: t+1 tile0 staged free
                // ---- issue next tile's global loads (unconditional) ----
                float4 wp[3];
                #pragma unroll
                for (int r = 0; r < 3; ++r)
                    wp[r] = *((const float4*)(w + wgoff[r] + itn * 24));

                const float* wsb = ws[it & 1];
                #pragma unroll
                for (int i4 = 0; i4 < 2; ++i4) {
                    float4 W0[4], W1[4], W2[4];
                    #pragma unroll
                    for (int oo = 0; oo < 4; ++oo) {
                        const float* wpt = wsb + ((oo * 6 + i4 * 3) * 32 + q4) * 4;
                        W0[oo] = *((const float4*)(wpt));
                        W1[oo] = *((const float4*)(wpt + 128));
                        W2[oo] = *((const float4*)(wpt + 256));
                    }

                    const int iic = itl * 2 + i4;                  // chunk-local group
                    const float4* xcol = (const float4*)xs + iic;  // stride 16/pos
                    float4 xa = xcol[(p0 + 0) * 16];
                    float4 xb = xcol[(p0 + 1) * 16];
                    #pragma unroll
                    for (int j = 0; j < JT; ++j) {
                        const float4 xc = xcol[(p0 + j + 2) * 16];
                        #pragma unroll
                        for (int oo = 0; oo < 4; ++oo) {
                            float s = a[oo][j];
                            const float4 w0 = W0[oo], w1 = W1[oo], w2 = W2[oo];
                            s = fmaf(xa.x, w0.x, s);   // k=0, i+0
                            s = fmaf(xa.y, w0.w, s);   // k=0, i+1
                            s = fmaf(xa.z, w1.z, s);   // k=0, i+2
                            s = fmaf(xa.w, w2.y, s);   // k=0, i+3
                            s = fmaf(xb.x, w0.y, s);   // k=1, i+0
                            s = fmaf(xb.y, w1.x, s);   // k=1, i+1
                            s = fmaf(xb.z, w1.w, s);   // k=1, i+2
                            s = fmaf(xb.w, w2.z, s);   // k=1, i+3
                            s = fmaf(xc.x, w0.z, s);   // k=2, i+0
                            s = fmaf(xc.y, w1.y, s);   // k=2, i+1
                            s = fmaf(xc.z, w2.x, s);   // k=2, i+2
                            s = fmaf(xc.w, w2.w, s);   // k=2, i+3
                            a[oo][j] = s;
                        }
                        xa = xb; xb = xc;
                    }
                }

                // ---- write prefetched tile into the OTHER buffer ----
                float* wsn = ws[itn & 1];
                #pragma unroll
                for (int r = 0; r < 3; ++r)
                    *((float4*)(&wsn[wloff[r]])) = wp[r];
                __syncthreads();   // one barrier per tile
            }
        }

        // ---- BN + LIF + residual (from global, L2-hot) + float4 store ----
        #pragma unroll
        for (int j = 0; j < JT; ++j) {
            const int l = l0 + p0 + j;
            const float4 res = x4[(l * NTB + n) * 32 + q4];
            const float rr[4] = {res.x, res.y, res.z, res.w};
            float ov[4];
            #pragma unroll
            for (int oo = 0; oo < 4; ++oo) {
                const float y = fmaf(a[oo][j], sc[oo], bi[oo]);
                const float h = 0.5f * (v[oo][j] + y);     // v + (y - v)/tau, tau=2
                const bool fire = (h >= 1.0f);
                v[oo][j] = fire ? 0.0f : h;                // hard reset
                ov[oo] = rr[oo] + (fire ? 1.0f : 0.0f);
            }
            ((float4*)out)[(l * NTB + n) * 32 + q4] =
                make_float4(ov[0], ov[1], ov[2], ov[3]);
        }
    }
}

extern "C" void kernel_launch(void* const* d_in, const int* in_sizes, int n_in,
                              void* d_out, int out_size, void* d_ws, size_t ws_size,
                              hipStream_t stream) {
    const float* x     = (const float*)d_in[0];
    const float* w     = (const float*)d_in[1];
    const float* gamma = (const float*)d_in[2];
    const float* beta  = (const float*)d_in[3];
    const float* mean  = (const float*)d_in[4];
    const float* var   = (const float*)d_in[5];
    float* out = (float*)d_out;

    dim3 grid((L / LT) * 32);   // 32 l-tiles x 32 b values = 1024 blocks
    dim3 block(256);
    snn_conv_lif<<<grid, block, 0, stream>>>(x, w, gamma, beta, mean, var, out);
}